// Round 16
// baseline (629.522 us; speedup 1.0000x reference)
//
#include <hip/hip_runtime.h>
#include <hip/hip_fp16.h>
#include <stdint.h>

#define N_NODES 50000
#define N_EDGES 800000
#define DIM_IN  16
#define H       512
#define GRAPHS  256

typedef __attribute__((ext_vector_type(8))) short short8;
typedef __attribute__((ext_vector_type(8))) _Float16 half8;
typedef __attribute__((ext_vector_type(4))) float f32x4;
typedef __attribute__((ext_vector_type(2))) float f32x2;
typedef __attribute__((ext_vector_type(4))) unsigned int u32x4;
typedef __attribute__((ext_vector_type(2))) unsigned int u32x2;

__device__ __forceinline__ unsigned short f2bf(float f) {
    unsigned int u = __float_as_uint(f);
    return (unsigned short)((u + 0x7fffu + ((u >> 16) & 1u)) >> 16);
}
__device__ __forceinline__ unsigned short f2h(float f) {
    __half h = __float2half(f);
    return *(unsigned short*)&h;
}

#define GLOAD_LDS16(g, l) __builtin_amdgcn_global_load_lds( \
    (const __attribute__((address_space(1))) void*)(g), \
    (__attribute__((address_space(3))) void*)(l), 16, 0, 0)

// ---------------- CSR build ----------------
__global__ void k_count(const int* __restrict__ ei, int* __restrict__ deg) {
    int t = blockIdx.x * 256 + threadIdx.x;
    if (t < N_EDGES) atomicAdd(&deg[ei[N_EDGES + t]], 1);
}

__global__ void k_scan1(const int* __restrict__ deg, int* __restrict__ off, int* __restrict__ bsum) {
    __shared__ int ls[512];
    int t = threadIdx.x; int gi = blockIdx.x * 512 + t;
    ls[t] = (gi < N_NODES) ? deg[gi] : 0;
    __syncthreads();
    for (int o = 1; o < 512; o <<= 1) {
        int u = (t >= o) ? ls[t - o] : 0;
        __syncthreads();
        ls[t] += u;
        __syncthreads();
    }
    if (gi < N_NODES) off[gi] = (t == 0) ? 0 : ls[t - 1];
    if (t == 511) bsum[blockIdx.x] = ls[511];
}

__global__ void k_scan2(int* bsum) {
    __shared__ int ls[128];
    int t = threadIdx.x;
    ls[t] = (t < 98) ? bsum[t] : 0;
    __syncthreads();
    for (int o = 1; o < 128; o <<= 1) {
        int u = (t >= o) ? ls[t - o] : 0;
        __syncthreads();
        ls[t] += u;
        __syncthreads();
    }
    if (t < 98) bsum[t] = (t == 0) ? 0 : ls[t - 1];
}

__global__ void k_scan3(int* __restrict__ off, const int* __restrict__ bsum, int* __restrict__ cur) {
    int i = blockIdx.x * 256 + threadIdx.x;
    if (i < N_NODES) {
        int v = off[i] + bsum[i >> 9];
        off[i] = v; cur[i] = v;
    }
    if (i == 0) off[N_NODES] = N_EDGES;
}

__global__ void k_fill(const int* __restrict__ ei, int* __restrict__ cur, int* __restrict__ csr) {
    int t = blockIdx.x * 256 + threadIdx.x;
    if (t < N_EDGES) {
        int d = ei[N_EDGES + t];
        int p = atomicAdd(&cur[d], 1);
        csr[p] = ei[t];
    }
}

// ---------------- input projection: h0 = x @ W_in + b_in -> fp8 mirror only ----------------
__global__ void k_gemm_in(const float* __restrict__ x, const float* __restrict__ Win,
                          const float* __restrict__ bin, unsigned char* __restrict__ h8) {
    __shared__ float Wl[DIM_IN * H];
    __shared__ float xl[16 * DIM_IN];
    __shared__ float bl[H];
    int t = threadIdx.x;
    const float4* W4 = (const float4*)Win;
    float4* Wl4 = (float4*)Wl;
#pragma unroll
    for (int i = 0; i < 8; i++) Wl4[t + 256 * i] = W4[t + 256 * i];
    bl[t] = bin[t]; bl[t + 256] = bin[t + 256];
    int r0 = blockIdx.x * 16;
    {
        int r = t >> 4, k = t & 15;
        int row = r0 + r;
        xl[t] = (row < N_NODES) ? x[row * DIM_IN + k] : 0.f;
    }
    __syncthreads();
    int c0 = t * 2;
    for (int r = 0; r < 16; r++) {
        int row = r0 + r;
        if (row >= N_NODES) break;
        float a0 = bl[c0], a1 = bl[c0 + 1];
#pragma unroll
        for (int k = 0; k < 16; k++) {
            float xv = xl[r * 16 + k];
            a0 += xv * Wl[k * 512 + c0];
            a1 += xv * Wl[k * 512 + c0 + 1];
        }
        unsigned int pk8 = (unsigned int)__builtin_amdgcn_cvt_pk_fp8_f32(a0, a1, 0, false);
        *(unsigned short*)&h8[(size_t)row * 512 + c0] = (unsigned short)(pk8 & 0xffffu);
    }
}

// ---------------- neighbor aggregation: agg[n] = sum_src h8[src] -> f16 [N][512] ----------
__global__ void k_aggregate(const int* __restrict__ off, const int* __restrict__ csr,
                            const unsigned char* __restrict__ h8, unsigned short* __restrict__ agg) {
    int w = threadIdx.x >> 6, lane = threadIdx.x & 63;
    int n = blockIdx.x * 4 + w;
    if (n >= N_NODES) return;
    int s = off[n], e = off[n + 1];
    float acc[8] = {0, 0, 0, 0, 0, 0, 0, 0};
    const unsigned char* Ab = h8 + (size_t)lane * 8;

#define ACC_FP8(vv) { \
    f32x2 p0 = __builtin_amdgcn_cvt_pk_f32_fp8((int)(vv)[0], false); \
    f32x2 p1 = __builtin_amdgcn_cvt_pk_f32_fp8((int)(vv)[0], true);  \
    f32x2 p2 = __builtin_amdgcn_cvt_pk_f32_fp8((int)(vv)[1], false); \
    f32x2 p3 = __builtin_amdgcn_cvt_pk_f32_fp8((int)(vv)[1], true);  \
    acc[0] += p0[0]; acc[1] += p0[1]; acc[2] += p1[0]; acc[3] += p1[1]; \
    acc[4] += p2[0]; acc[5] += p2[1]; acc[6] += p3[0]; acc[7] += p3[1]; }

    for (int base = s; base < e; base += 64) {
        int m = e - base; if (m > 64) m = 64;
        int idx = (lane < m) ? csr[base + lane] : 0;
        int g = 0;
        for (; g + 4 <= m; g += 4) {
            int sn0 = __shfl(idx, g);
            int sn1 = __shfl(idx, g + 1);
            int sn2 = __shfl(idx, g + 2);
            int sn3 = __shfl(idx, g + 3);
            u32x2 v0 = *(const u32x2*)(Ab + ((size_t)sn0 << 9));
            u32x2 v1 = *(const u32x2*)(Ab + ((size_t)sn1 << 9));
            u32x2 v2 = *(const u32x2*)(Ab + ((size_t)sn2 << 9));
            u32x2 v3 = *(const u32x2*)(Ab + ((size_t)sn3 << 9));
            ACC_FP8(v0); ACC_FP8(v1); ACC_FP8(v2); ACC_FP8(v3);
        }
        for (; g < m; g++) {
            int sn = __shfl(idx, g);
            u32x2 v = *(const u32x2*)(Ab + ((size_t)sn << 9));
            ACC_FP8(v);
        }
    }
#undef ACC_FP8
    u32x4 hv;
#pragma unroll
    for (int j = 0; j < 4; j++) {
        hv[j] = ((unsigned int)f2h(acc[2 * j + 1]) << 16) | (unsigned int)f2h(acc[2 * j]);
    }
    *(u32x4*)&agg[(size_t)n * 512 + lane * 8] = hv;
}

// ---------------- fused conv GEMM + bias + LN + ReLU (fp8 root half + f16 agg half) --------
// 64 rows x 512 cols, 512 thr = 8 waves; wave = 16 rows x 256 cols (16 frags).
// Phase 1 (8 pair-steps): 2 fp8 kts per barrier pair (32KB B-stage = 2x16KB, 32 mfma/wave).
// Phase 2 (16 steps): f16 agg kts, 32KB B-stage each.  Barrier pairs: 24 vs 32 at BK=32.
// A operands direct global->register, prefetched into NEXT regs; R6-proven sync skeleton.
__global__ __launch_bounds__(512, 4)
void k_gemm_layer(const unsigned char* __restrict__ h8in, const unsigned short* __restrict__ agg,
                  unsigned char* __restrict__ h8out, unsigned short* __restrict__ hout,
                  const unsigned char* __restrict__ Bp8, const unsigned short* __restrict__ Bpf,
                  const float* __restrict__ bias, const float* __restrict__ gamma,
                  const float* __restrict__ beta, int lastLayer) {
    extern __shared__ __align__(16) char smem[];   // 2 x 32KB B slots
    int t = threadIdx.x, w = t >> 6, lane = t & 63;
    int wr = w >> 1, wc = w & 1;
    int rblk = blockIdx.x * 64;

    f32x4 acc[16];
#pragma unroll
    for (int i = 0; i < 16; i++) acc[i] = (f32x4)(0.f);

    int rowA = rblk + wr * 16 + (lane & 15);
    if (rowA >= N_NODES) rowA = N_NODES - 1;
    const unsigned char* aRow8 = h8in + (size_t)rowA * 512 + (lane >> 4) * 8;
    const unsigned char* aRowF = (const unsigned char*)agg + (size_t)rowA * 1024 + (lane >> 4) * 16;
    const unsigned char* BpfB = (const unsigned char*)Bpf;

    // stage one fp8 PAIR (2 kts = 32KB, linear copy): 512 thr x 64B
    auto STAGE8P = [&](int ktp, int buf) {
        const unsigned char* g = Bp8 + (size_t)ktp * 32768 + w * 4096 + lane * 16;
        char* base = smem + buf * 32768 + w * 4096;
#pragma unroll
        for (int j = 0; j < 4; j++) GLOAD_LDS16(g + j * 1024, base + j * 1024);
    };
    auto STAGEF = [&](int ktf, int buf) {
        const unsigned char* g = BpfB + (size_t)ktf * 32768 + lane * 16;
        char* base = smem + buf * 32768;
#pragma unroll
        for (int i = 0; i < 4; i++) {
            int cf = w * 4 + i;
            GLOAD_LDS16(g + cf * 1024, base + cf * 1024);
        }
    };

    long a8c0 = *(const long*)(aRow8);
    long a8c1 = *(const long*)(aRow8 + 32);
    long a8n0 = 0, a8n1 = 0;
    half8 a16c = (half8)(_Float16)0, a16n = (half8)(_Float16)0;
    STAGE8P(0, 0);
    __syncthreads();

    // ---- phase 1: 8 fp8 pair-steps ----
    for (int ktp = 0; ktp < 8; ktp++) {
        int cur = ktp & 1;
        if (ktp < 7) {
            a8n0 = *(const long*)(aRow8 + (2 * ktp + 2) * 32);
            a8n1 = *(const long*)(aRow8 + (2 * ktp + 3) * 32);
            STAGE8P(ktp + 1, cur ^ 1);
        } else {
            a16n = *(const half8*)(aRowF);
            STAGEF(0, cur ^ 1);
        }
        char* base = smem + cur * 32768;
#pragma unroll
        for (int i = 0; i < 16; i++) {
            long bv = *(const long*)(base + (wc * 16 + i) * 512 + lane * 8);
            acc[i] = __builtin_amdgcn_mfma_f32_16x16x32_fp8_fp8(a8c0, bv, acc[i], 0, 0, 0);
        }
#pragma unroll
        for (int i = 0; i < 16; i++) {
            long bv = *(const long*)(base + 16384 + (wc * 16 + i) * 512 + lane * 8);
            acc[i] = __builtin_amdgcn_mfma_f32_16x16x32_fp8_fp8(a8c1, bv, acc[i], 0, 0, 0);
        }
        __syncthreads();
        a8c0 = a8n0; a8c1 = a8n1;
        a16c = a16n;
    }

    // ---- phase 2: 16 f16 steps ----
    for (int f = 0; f < 16; f++) {
        int cur = f & 1;
        if (f < 15) {
            a16n = *(const half8*)(aRowF + (f + 1) * 64);
            STAGEF(f + 1, cur ^ 1);
        }
        char* base = smem + cur * 32768;
#pragma unroll
        for (int i = 0; i < 16; i++) {
            half8 bv = *(const half8*)(base + (wc * 16 + i) * 1024 + lane * 16);
            acc[i] = __builtin_amdgcn_mfma_f32_16x16x32_f16(a16c, bv, acc[i], 0, 0, 0);
        }
        __syncthreads();
        a16c = a16n;
    }

    // ---- epilogue: bias + LN (cross-wave over 2 col-halves) + ReLU ----
    int g = lane >> 4, cl = lane & 15;
    float s[4] = {0, 0, 0, 0}, q[4] = {0, 0, 0, 0};
#pragma unroll
    for (int i = 0; i < 16; i++) {
        int col = wc * 256 + i * 16 + cl;
        float b = bias[col];
        f32x4 a = acc[i];
#pragma unroll
        for (int r = 0; r < 4; r++) {
            float v = a[r] + b;
            a[r] = v;
            s[r] += v;
            q[r] += v * v;
        }
        acc[i] = a;
    }
#pragma unroll
    for (int m = 1; m < 16; m <<= 1) {
#pragma unroll
        for (int r = 0; r < 4; r++) {
            s[r] += __shfl_xor(s[r], m);
            q[r] += __shfl_xor(q[r], m);
        }
    }
    float* pbuf = (float*)smem;
    if (cl == 0) {
#pragma unroll
        for (int r = 0; r < 4; r++) {
            pbuf[((wr * 2 + wc) * 16) + g * 4 + r] = s[r];
            pbuf[256 + ((wr * 2 + wc) * 16) + g * 4 + r] = q[r];
        }
    }
    __syncthreads();
    float mean[4], rs[4];
#pragma unroll
    for (int r = 0; r < 4; r++) {
        float sf = pbuf[(wr * 2) * 16 + g * 4 + r] + pbuf[(wr * 2 + 1) * 16 + g * 4 + r];
        float qf = pbuf[256 + (wr * 2) * 16 + g * 4 + r] + pbuf[256 + (wr * 2 + 1) * 16 + g * 4 + r];
        mean[r] = sf * (1.f / 512.f);
        float var = qf * (1.f / 512.f) - mean[r] * mean[r];
        rs[r] = rsqrtf(var + 1e-5f);
    }
    __syncthreads();   // pbuf reads done before smem reuse below
    int row0 = rblk + wr * 16 + g * 4;
    if (lastLayer) {
        bool ok[4];
#pragma unroll
        for (int r = 0; r < 4; r++) ok[r] = (row0 + r) < N_NODES;
#pragma unroll
        for (int i = 0; i < 16; i++) {
            int col = wc * 256 + i * 16 + cl;
            float ga = gamma[col], be = beta[col];
            f32x4 a = acc[i];
#pragma unroll
            for (int r = 0; r < 4; r++) {
                float o = (a[r] - mean[r]) * rs[r] * ga + be;
                o = fmaxf(o, 0.f);
                if (ok[r]) hout[(size_t)(row0 + r) * 512 + col] = f2bf(o);
            }
        }
    } else {
        // stage fp8 tile in LDS (64 rows x 512 B), then coalesced copy-out
#pragma unroll
        for (int i = 0; i < 16; i++) {
            int col = wc * 256 + i * 16 + cl;
            float ga = gamma[col], be = beta[col];
            f32x4 a = acc[i];
#pragma unroll
            for (int r = 0; r < 4; r++) {
                float o = (a[r] - mean[r]) * rs[r] * ga + be;
                o = fmaxf(o, 0.f);
                unsigned int pk8 = (unsigned int)__builtin_amdgcn_cvt_pk_fp8_f32(o, o, 0, false);
                smem[(wr * 16 + g * 4 + r) * 512 + col] = (char)(pk8 & 0xffu);
            }
        }
        __syncthreads();
        int row = t >> 3, off = (t & 7) * 64;
        if (rblk + row < N_NODES) {
            unsigned char* dst = h8out + (size_t)(rblk + row) * 512 + off;
            const char* src = smem + row * 512 + off;
#pragma unroll
            for (int j = 0; j < 4; j++) {
                u32x4 v = *(const u32x4*)(src + j * 16);
                *(u32x4*)(dst + j * 16) = v;
            }
        }
    }
}

// ---------------- mean pool per graph (batch sorted) ----------------
__global__ void k_pool(const unsigned short* __restrict__ hbf, const int* __restrict__ batch,
                       float* __restrict__ pooled) {
    __shared__ float part[4 * 512];
    __shared__ int se[2];
    int g = blockIdx.x, t = threadIdx.x, w = t >> 6, lane = t & 63;
    if (t == 0) {
        int lo = 0, hi = N_NODES;
        while (lo < hi) { int m = (lo + hi) >> 1; if (batch[m] < g) lo = m + 1; else hi = m; }
        se[0] = lo;
        int lo2 = lo; hi = N_NODES;
        while (lo2 < hi) { int m = (lo2 + hi) >> 1; if (batch[m] < g + 1) lo2 = m + 1; else hi = m; }
        se[1] = lo2;
    }
    __syncthreads();
    int s = se[0], e = se[1];
    float acc[8] = {0, 0, 0, 0, 0, 0, 0, 0};
    for (int row = s + w; row < e; row += 4) {
        u32x4 v = *(const u32x4*)&hbf[(size_t)row * 512 + lane * 8];
#pragma unroll
        for (int j = 0; j < 4; j++) {
            unsigned int uu = v[j];
            acc[2 * j]     += __uint_as_float(uu << 16);
            acc[2 * j + 1] += __uint_as_float(uu & 0xffff0000u);
        }
    }
#pragma unroll
    for (int j = 0; j < 8; j++) part[w * 512 + j * 64 + lane] = acc[j];
    __syncthreads();
    float cnt = fmaxf((float)(e - s), 1.f);
    for (int sidx = t; sidx < 512; sidx += 256) {
        float v = part[sidx] + part[512 + sidx] + part[1024 + sidx] + part[1536 + sidx];
        int col = (sidx & 63) * 8 + (sidx >> 6);
        pooled[(size_t)g * 512 + col] = v / cnt;
    }
}

// ---------------- final: out = pooled @ W_out + b_out (fp32), 8 graphs/block ----------------
__global__ __launch_bounds__(256)
void k_out(const float* __restrict__ pooled, const float* __restrict__ Wout,
           const float* __restrict__ bout, float* __restrict__ out) {
    __shared__ float pl[8 * 512];
    int t = threadIdx.x;
    int g0 = blockIdx.x * 8;
#pragma unroll
    for (int i = 0; i < 16; i++) {
        int idx = i * 256 + t;
        pl[idx] = pooled[(size_t)g0 * 512 + idx];
    }
    __syncthreads();
    int c0 = t * 2;
    float a[8][2];
#pragma unroll
    for (int g = 0; g < 8; g++) { a[g][0] = bout[c0]; a[g][1] = bout[c0 + 1]; }
    for (int k = 0; k < 512; k++) {
        float2 wv = *(const float2*)&Wout[(size_t)k * 512 + c0];
#pragma unroll
        for (int g = 0; g < 8; g++) {
            float p = pl[g * 512 + k];
            a[g][0] += p * wv.x;
            a[g][1] += p * wv.y;
        }
    }
#pragma unroll
    for (int g = 0; g < 8; g++) {
        out[(size_t)(g0 + g) * 512 + c0]     = a[g][0];
        out[(size_t)(g0 + g) * 512 + c0 + 1] = a[g][1];
    }
}

// ---------------- pack B: W_root -> fp8 frag order, W_neigh -> f16 frag order --------------
__global__ void k_pack_b(const float* __restrict__ Wr, const float* __restrict__ Wn,
                         unsigned char* __restrict__ Bp8, unsigned short* __restrict__ Bpf) {
    int tid = blockIdx.x * 256 + threadIdx.x;
    const int HALF = 3 * 16 * 32 * 64;
    if (tid >= 2 * HALF) return;
    bool isRoot = (tid < HALF);
    int t = isRoot ? tid : tid - HALF;
    int lane = t & 63;
    int u = t >> 6;
    int cf = u & 31; u >>= 5;
    int kt = u & 15;
    int l  = u >> 4;
    int col = cf * 16 + (lane & 15);
    int kr0 = kt * 32 + (lane >> 4) * 8;
    if (isRoot) {
        const float* W = Wr + (size_t)l * H * H;
        float v[8];
#pragma unroll
        for (int j = 0; j < 8; j++) v[j] = W[(size_t)(kr0 + j) * H + col];
        int w0 = __builtin_amdgcn_cvt_pk_fp8_f32(v[0], v[1], 0, false);
        w0 = __builtin_amdgcn_cvt_pk_fp8_f32(v[2], v[3], w0, true);
        int w1 = __builtin_amdgcn_cvt_pk_fp8_f32(v[4], v[5], 0, false);
        w1 = __builtin_amdgcn_cvt_pk_fp8_f32(v[6], v[7], w1, true);
        u32x2 o; o[0] = (unsigned int)w0; o[1] = (unsigned int)w1;
        *(u32x2*)&Bp8[(size_t)((l * 16 + kt) * 32 + cf) * 512 + lane * 8] = o;
    } else {
        const float* W = Wn + (size_t)l * H * H;
        unsigned int words[4];
#pragma unroll
        for (int p = 0; p < 4; p++) {
            float v0 = W[(size_t)(kr0 + 2 * p) * H + col];
            float v1 = W[(size_t)(kr0 + 2 * p + 1) * H + col];
            words[p] = ((unsigned int)f2h(v1) << 16) | (unsigned int)f2h(v0);
        }
        u32x4 v; v[0] = words[0]; v[1] = words[1]; v[2] = words[2]; v[3] = words[3];
        *(u32x4*)&Bpf[(size_t)((l * 16 + kt) * 32 + cf) * 512 + lane * 8] = v;
    }
}

extern "C" void kernel_launch(void* const* d_in, const int* in_sizes, int n_in,
                              void* d_out, int out_size, void* d_ws, size_t ws_size,
                              hipStream_t stream) {
    const float* x     = (const float*)d_in[0];
    const int*   ei    = (const int*)d_in[1];
    const int*   batch = (const int*)d_in[2];
    const float* Win   = (const float*)d_in[3];
    const float* bin   = (const float*)d_in[4];
    const float* Wr    = (const float*)d_in[5];
    const float* Wn    = (const float*)d_in[6];
    const float* bconv = (const float*)d_in[7];
    const float* gamma = (const float*)d_in[8];
    const float* beta  = (const float*)d_in[9];
    const float* Wout  = (const float*)d_in[10];
    const float* bout  = (const float*)d_in[11];
    float* out = (float*)d_out;

    char* p = (char*)d_ws;
    auto carve = [&](size_t bytes) { char* r = p; p += (bytes + 255) & ~(size_t)255; return r; };
    unsigned char*  h8a  = (unsigned char*)carve((size_t)N_NODES * 512);
    unsigned char*  h8b  = (unsigned char*)carve((size_t)N_NODES * 512);
    unsigned short* agg  = (unsigned short*)carve((size_t)N_NODES * 512 * 2);
    unsigned short* hout = (unsigned short*)carve((size_t)N_NODES * 512 * 2);
    unsigned char*  Bp8  = (unsigned char*)carve((size_t)3 * 16 * 32 * 64 * 8);
    unsigned short* Bpf  = (unsigned short*)carve((size_t)3 * 16 * 32 * 64 * 8 * 2);
    int* csr  = (int*)carve((size_t)N_EDGES * 4);
    int* deg  = (int*)carve((size_t)N_NODES * 4);
    int* off  = (int*)carve((size_t)(N_NODES + 1) * 4);
    int* cur  = (int*)carve((size_t)N_NODES * 4);
    int* bsum = (int*)carve(1024);
    float* pooled = (float*)carve((size_t)GRAPHS * H * 4);

    hipMemsetAsync(deg, 0, (size_t)N_NODES * 4, stream);
    k_count<<<(N_EDGES + 255) / 256, 256, 0, stream>>>(ei, deg);
    k_scan1<<<98, 512, 0, stream>>>(deg, off, bsum);
    k_scan2<<<1, 128, 0, stream>>>(bsum);
    k_scan3<<<(N_NODES + 255) / 256, 256, 0, stream>>>(off, bsum, cur);
    k_fill<<<(N_EDGES + 255) / 256, 256, 0, stream>>>(ei, cur, csr);
    k_gemm_in<<<(N_NODES + 15) / 16, 256, 0, stream>>>(x, Win, bin, h8a);
    k_pack_b<<<(2 * 3 * 16 * 32 * 64 + 255) / 256, 256, 0, stream>>>(Wr, Wn, Bp8, Bpf);

    unsigned char* hcur = h8a;
    unsigned char* hnxt = h8b;
    for (int l = 0; l < 3; l++) {
        k_aggregate<<<(N_NODES + 3) / 4, 256, 0, stream>>>(off, csr, hcur, agg);
        k_gemm_layer<<<(N_NODES + 63) / 64, 512, 65536, stream>>>(
            hcur, agg, hnxt, hout,
            Bp8 + (size_t)l * 16 * 16384, Bpf + (size_t)l * 16 * 16384,
            bconv + (size_t)l * H, gamma + (size_t)l * H, beta + (size_t)l * H,
            (l == 2) ? 1 : 0);
        unsigned char* tmp = hcur; hcur = hnxt; hnxt = tmp;
    }
    k_pool<<<GRAPHS, 256, 0, stream>>>(hout, batch, pooled);
    k_out<<<32, 256, 0, stream>>>(pooled, Wout, bout, out);
}